// Round 17
// baseline (77.987 us; speedup 1.0000x reference)
//
#include <hip/hip_runtime.h>
#include <hip/hip_bf16.h>
#include <stdint.h>

#define B_ 32
#define S_ 8192
#define HD_ 256
#define HE_ 256
#define CHUNK 512
#define ROWS 16              /* rows per tile */
#define MSTEPS (CHUNK/ROWS)  /* 32 tiles */
#define NITER (MSTEPS/2)     /* 16 iterations, 2 tiles each */
#define NCHUNK (S_/CHUNK)    /* 16 chunks per batch */
#define TILE (ROWS * 512)    /* 8 KB per keys tile */

typedef __attribute__((ext_vector_type(8))) short bf16x8;
typedef __attribute__((ext_vector_type(4))) float f32x4;

__device__ __forceinline__ uint32_t cvt_pk_bf16(float lo, float hi) {
  uint32_t r;
  asm("v_cvt_pk_bf16_f32 %0, %1, %2" : "=v"(r) : "v"(lo), "v"(hi));
  return r;
}
__device__ __forceinline__ float bf2f(unsigned short h) {
  return __uint_as_float(((uint32_t)h) << 16);
}
__device__ __forceinline__ float tanh_fast(float x) {
  // tanh(x) = 1 - 2/(exp(2x)+1); well-behaved at +/-inf, no NaN
  float e = __expf(2.0f * x);
  return 1.0f - 2.0f * __builtin_amdgcn_rcpf(e + 1.0f);
}
// VALU cross-lane add within 16-lane DPP rows. Sum lands in lane 15 of each row.
template<int CTRL>
__device__ __forceinline__ float dpp_shr_add(float v) {
  int t = __builtin_amdgcn_update_dpp(0, __float_as_int(v), CTRL, 0xf, 0xf, true);
  return v + __int_as_float(t);
}
__device__ __forceinline__ float row16_sum(float v) {
  v = dpp_shr_add<0x118>(v);   // row_shr:8
  v = dpp_shr_add<0x114>(v);   // row_shr:4
  v = dpp_shr_add<0x112>(v);   // row_shr:2
  v = dpp_shr_add<0x111>(v);   // row_shr:1
  return v;                     // full sum valid in lane 15 of each 16-lane row
}

// ---------------- prep: qv[b,h] = q@Wa^T + Wa_b + Ua_b ; Ua -> bf16 ----------------
__global__ void prep_kernel(const float* __restrict__ query,
                            const float* __restrict__ Wa_w,
                            const float* __restrict__ Wa_b,
                            const float* __restrict__ Ua_w,
                            const float* __restrict__ Ua_b,
                            float* __restrict__ qv,
                            unsigned short* __restrict__ ua_bf) {
  const int blk = blockIdx.x, t = threadIdx.x;
  if (blk < B_) {
    __shared__ float qs[HD_];
    qs[t] = query[blk * HD_ + t];
    __syncthreads();
    const float* wr = Wa_w + (size_t)t * HD_;
    float s = Wa_b[t] + Ua_b[t];
#pragma unroll 8
    for (int d = 0; d < HD_; ++d) s += qs[d] * wr[d];
    qv[blk * HD_ + t] = s;
  } else {
    const int base = (blk - B_) * 2048 + t * 8;
    float4 v0 = *(const float4*)(Ua_w + base);
    float4 v1 = *(const float4*)(Ua_w + base + 4);
    uint4 pk;
    pk.x = cvt_pk_bf16(v0.x, v0.y);
    pk.y = cvt_pk_bf16(v0.z, v0.w);
    pk.z = cvt_pk_bf16(v1.x, v1.y);
    pk.w = cvt_pk_bf16(v1.z, v1.w);
    *(uint4*)(ua_bf + base) = pk;
  }
}

// ---------------- main: fused k_proj GEMM + tanh + score-exp + context partial ----------------
// v18 = v17 (two tiles per barrier, 16 barriers/block) with the epilogue slot fix:
// after the loop base == (2*NITER)%6 == 2, and tiles 30/31 live in slots tl%6 == 0/1.
// Keys LDS 6-buffered (iteration j: read cur slots 2j,2j+1 mod 6; read num slots
// 2j+4,2j+5 (tiles 2j-2,2j-1); write slots 2j+2,2j+3 -- all distinct; every
// cross-iteration reuse separated by a barrier). sc 6-slotted identically. Single
// g-register set reused twice per iteration keeps arch VGPR at 64 (no overdraft).
__global__ __launch_bounds__(512)
__attribute__((amdgpu_waves_per_eu(4, 4)))
void main_kernel(const float* __restrict__ keys,
                 const float* __restrict__ qv,
                 const float* __restrict__ Va_w,
                 const unsigned short* __restrict__ ua_bf,
                 float* __restrict__ wexp_g,
                 float* __restrict__ partials) {
  __shared__ __align__(16) char kt[6 * TILE];          // 6 x (16 rows x 512B bf16), swizzled
  __shared__ float sc6[6][16];                          // 6-slot row scores
  __shared__ float wexp_l[CHUNK];                       // per-chunk exp(score), flushed at end
  __shared__ __align__(16) float num_l[8][64][4];       // per-wave numerator partials (8 KB)

  const int t = threadIdx.x;
  const int b = blockIdx.y;
  const int chunk = blockIdx.x;
  const int s0 = chunk * CHUNK;
  const int lane = t & 63;
  const int w = t >> 6;               // wave 0..7
  const int ln = lane & 15;
  const int hi = lane >> 4;

  // ---- B fragments: wave w's 32 h-cols, 2 h-tiles, read ONCE (64 regs) ----
  const unsigned short* ub0 = ua_bf + (size_t)(w * 32 + ln) * HE_ + hi * 8;
  const unsigned short* ub1 = ub0 + 16 * HE_;
  bf16x8 bb0[8], bb1[8];
#pragma unroll
  for (int k = 0; k < 8; ++k) {
    bb0[k] = *(const bf16x8*)(ub0 + k * 32);
    bb1[k] = *(const bf16x8*)(ub1 + k * 32);
  }
  const float q0  = qv[b * HD_ + w * 32 + ln];
  const float q1  = qv[b * HD_ + w * 32 + 16 + ln];
  const float va0 = Va_w[w * 32 + ln];
  const float va1 = Va_w[w * 32 + 16 + ln];

  // ---- staging geometry: thread t handles row t>>5, 16B bf16 chunk t&31 ----
  const int srow = t >> 5;            // 0..15
  const int scch = t & 31;            // 16B bf16 chunk within 512B row
  const float* ksrc = keys + ((size_t)b * S_ + s0 + srow) * HE_ + scch * 8;
  const int ldsoff = srow * 512 + ((scch * 16) ^ ((srow & 7) << 4));

  // ---- prologue: zero all sc6; stage tiles 0 and 1 ----
  if (t < 96) ((float*)sc6)[t] = 0.f;
#pragma unroll
  for (int tl = 0; tl < 2; ++tl) {
    const float* kA = ksrc + (size_t)tl * ROWS * HE_;
    float4 a0 = *(const float4*)(kA);
    float4 a1 = *(const float4*)(kA + 4);
    uint4 pk;
    pk.x = cvt_pk_bf16(a0.x, a0.y);
    pk.y = cvt_pk_bf16(a0.z, a0.w);
    pk.z = cvt_pk_bf16(a1.x, a1.y);
    pk.w = cvt_pk_bf16(a1.z, a1.w);
    *(uint4*)(kt + tl * TILE + ldsoff) = pk;
  }
  __syncthreads();

  const int asw = (ln & 7) << 4;      // A-frag row swizzle
  const int nsw = (w & 7) << 4;       // numerator row swizzle ((w+8)&7 == w&7)
  float num4[4] = {0.f, 0.f, 0.f, 0.f};
  int base = 0;                       // (2j) % 6

  for (int j = 0; j < NITER; ++j) {
    const int s_cur0 = base;
    const int s_cur1 = base + 1;
    int s_stg0 = base + 2; if (s_stg0 >= 6) s_stg0 -= 6;
    int s_stg1 = base + 3; if (s_stg1 >= 6) s_stg1 -= 6;
    int s_prv0 = base + 4; if (s_prv0 >= 6) s_prv0 -= 6;
    int s_prv1 = base + 5; if (s_prv1 >= 6) s_prv1 -= 6;
    const int i0 = 2 * j;

    // ================= Phase A: tile 2j =================
    float4 ga0, ga1;
    if (i0 + 2 < MSTEPS) {            // issue loads for tile 2j+2
      const float* kA = ksrc + (size_t)(i0 + 2) * ROWS * HE_;
      ga0 = *(const float4*)(kA);
      ga1 = *(const float4*)(kA + 4);
    }

    {
      f32x4 a00 = {0.f,0.f,0.f,0.f}, a01 = {0.f,0.f,0.f,0.f};
      const char* arow = kt + s_cur0 * TILE + ln * 512;
#pragma unroll
      for (int k = 0; k < 8; ++k) {
        bf16x8 af = *(const bf16x8*)(arow + ((k * 64 + hi * 16) ^ asw));
        a00 = __builtin_amdgcn_mfma_f32_16x16x32_bf16(af, bb0[k], a00, 0, 0, 0);
        a01 = __builtin_amdgcn_mfma_f32_16x16x32_bf16(af, bb1[k], a01, 0, 0, 0);
      }
      // lagged exp + wexp + numerator for tile 2j-2
      if (j > 0) {
        const float* scp = sc6[s_prv0];
        const char* prv = kt + s_prv0 * TILE;
        const float e0 = __expf(scp[w]);
        const float e8 = __expf(scp[w + 8]);
        if (lane == 0) {
          wexp_l[(i0 - 2) * ROWS + w] = e0;
          wexp_l[(i0 - 2) * ROWS + 8 + w] = e8;
        }
        uint2 kv0 = *(const uint2*)(prv + w * 512 + ((lane * 8) ^ nsw));
        uint2 kv1 = *(const uint2*)(prv + (w + 8) * 512 + ((lane * 8) ^ nsw));
        num4[0] += e0 * bf2f((unsigned short)(kv0.x & 0xffff)) + e8 * bf2f((unsigned short)(kv1.x & 0xffff));
        num4[1] += e0 * bf2f((unsigned short)(kv0.x >> 16))    + e8 * bf2f((unsigned short)(kv1.x >> 16));
        num4[2] += e0 * bf2f((unsigned short)(kv0.y & 0xffff)) + e8 * bf2f((unsigned short)(kv1.y & 0xffff));
        num4[3] += e0 * bf2f((unsigned short)(kv0.y >> 16))    + e8 * bf2f((unsigned short)(kv1.y >> 16));
      }
      // tanh + DPP reduce + atomic into sc[2j]
#pragma unroll
      for (int r = 0; r < 4; ++r) {
        float v = tanh_fast(a00[r] + q0) * va0 + tanh_fast(a01[r] + q1) * va1;
        v = row16_sum(v);
        if (ln == 15) atomicAdd(&sc6[s_cur0][hi * 4 + r], v);
      }
      // stage-write tile 2j+2
      if (i0 + 2 < MSTEPS) {
        uint4 pk;
        pk.x = cvt_pk_bf16(ga0.x, ga0.y);
        pk.y = cvt_pk_bf16(ga0.z, ga0.w);
        pk.z = cvt_pk_bf16(ga1.x, ga1.y);
        pk.w = cvt_pk_bf16(ga1.z, ga1.w);
        *(uint4*)(kt + s_stg0 * TILE + ldsoff) = pk;
      }
    }

    // ================= Phase B: tile 2j+1 =================
    if (i0 + 3 < MSTEPS) {            // issue loads for tile 2j+3 (g regs now free)
      const float* kA = ksrc + (size_t)(i0 + 3) * ROWS * HE_;
      ga0 = *(const float4*)(kA);
      ga1 = *(const float4*)(kA + 4);
    }

    {
      f32x4 a00 = {0.f,0.f,0.f,0.f}, a01 = {0.f,0.f,0.f,0.f};
      const char* arow = kt + s_cur1 * TILE + ln * 512;
#pragma unroll
      for (int k = 0; k < 8; ++k) {
        bf16x8 af = *(const bf16x8*)(arow + ((k * 64 + hi * 16) ^ asw));
        a00 = __builtin_amdgcn_mfma_f32_16x16x32_bf16(af, bb0[k], a00, 0, 0, 0);
        a01 = __builtin_amdgcn_mfma_f32_16x16x32_bf16(af, bb1[k], a01, 0, 0, 0);
      }
      // lagged exp + wexp + numerator for tile 2j-1
      if (j > 0) {
        const float* scp = sc6[s_prv1];
        const char* prv = kt + s_prv1 * TILE;
        const float e0 = __expf(scp[w]);
        const float e8 = __expf(scp[w + 8]);
        if (lane == 0) {
          wexp_l[(i0 - 1) * ROWS + w] = e0;
          wexp_l[(i0 - 1) * ROWS + 8 + w] = e8;
        }
        uint2 kv0 = *(const uint2*)(prv + w * 512 + ((lane * 8) ^ nsw));
        uint2 kv1 = *(const uint2*)(prv + (w + 8) * 512 + ((lane * 8) ^ nsw));
        num4[0] += e0 * bf2f((unsigned short)(kv0.x & 0xffff)) + e8 * bf2f((unsigned short)(kv1.x & 0xffff));
        num4[1] += e0 * bf2f((unsigned short)(kv0.x >> 16))    + e8 * bf2f((unsigned short)(kv1.x >> 16));
        num4[2] += e0 * bf2f((unsigned short)(kv0.y & 0xffff)) + e8 * bf2f((unsigned short)(kv1.y & 0xffff));
        num4[3] += e0 * bf2f((unsigned short)(kv0.y >> 16))    + e8 * bf2f((unsigned short)(kv1.y >> 16));
      }
      // tanh + DPP reduce + atomic into sc[2j+1]
#pragma unroll
      for (int r = 0; r < 4; ++r) {
        float v = tanh_fast(a00[r] + q0) * va0 + tanh_fast(a01[r] + q1) * va1;
        v = row16_sum(v);
        if (ln == 15) atomicAdd(&sc6[s_cur1][hi * 4 + r], v);
      }
      // zero the two sc slots written next iteration (unread this iteration)
      if (t < 16) sc6[s_stg0][t] = 0.f;
      else if (t < 32) sc6[s_stg1][t - 16] = 0.f;
      // stage-write tile 2j+3
      if (i0 + 3 < MSTEPS) {
        uint4 pk;
        pk.x = cvt_pk_bf16(ga0.x, ga0.y);
        pk.y = cvt_pk_bf16(ga0.z, ga0.w);
        pk.z = cvt_pk_bf16(ga1.x, ga1.y);
        pk.w = cvt_pk_bf16(ga1.z, ga1.w);
        *(uint4*)(kt + s_stg1 * TILE + ldsoff) = pk;
      }
    }

    base += 2; if (base >= 6) base -= 6;
    __syncthreads();   // single barrier: publishes sc[2j],sc[2j+1] + buf[2j+2],buf[2j+3]
  }

  // ---- epilogue: tiles MSTEPS-2, MSTEPS-1 in slots (tile % 6) ----
#pragma unroll
  for (int f = 0; f < 2; ++f) {
    const int tl = MSTEPS - 2 + f;
    const int slot = tl % 6;                   // tiles 30,31 -> slots 0,1 (base ends at 2)
    const float* scp = sc6[slot];
    const char* prv = kt + slot * TILE;
    const float e0 = __expf(scp[w]);
    const float e8 = __expf(scp[w + 8]);
    if (lane == 0) {
      wexp_l[tl * ROWS + w] = e0;
      wexp_l[tl * ROWS + 8 + w] = e8;
    }
    uint2 kv0 = *(const uint2*)(prv + w * 512 + ((lane * 8) ^ nsw));
    uint2 kv1 = *(const uint2*)(prv + (w + 8) * 512 + ((lane * 8) ^ nsw));
    num4[0] += e0 * bf2f((unsigned short)(kv0.x & 0xffff)) + e8 * bf2f((unsigned short)(kv1.x & 0xffff));
    num4[1] += e0 * bf2f((unsigned short)(kv0.x >> 16))    + e8 * bf2f((unsigned short)(kv1.x >> 16));
    num4[2] += e0 * bf2f((unsigned short)(kv0.y & 0xffff)) + e8 * bf2f((unsigned short)(kv1.y & 0xffff));
    num4[3] += e0 * bf2f((unsigned short)(kv0.y >> 16))    + e8 * bf2f((unsigned short)(kv1.y >> 16));
  }

  // ---- flush wexp + cross-wave numerator reduce ----
  *(float4*)&num_l[w][lane][0] = make_float4(num4[0], num4[1], num4[2], num4[3]);
  __syncthreads();
  wexp_g[(size_t)b * S_ + s0 + t] = wexp_l[t];   // CHUNK == blockDim: one coalesced store
  if (t < 256) {
    float s = 0.f;
#pragma unroll
    for (int ww = 0; ww < 8; ++ww) s += num_l[ww][t >> 2][t & 3];
    partials[((size_t)b * NCHUNK + chunk) * 256 + t] = s;
  }
}

// ---------------- combine: den + context + weights per batch ----------------
__global__ void combine_kernel(const float* __restrict__ wexp_g,
                               const float* __restrict__ partials,
                               float* __restrict__ out) {
  __shared__ float red[4];
  __shared__ float rdsh;
  const int b = blockIdx.x, t = threadIdx.x;   // 256 threads
  const float* we = wexp_g + (size_t)b * S_;
  float s = 0.f;
#pragma unroll 4
  for (int i = t; i < S_; i += 256) s += we[i];
#pragma unroll
  for (int mm = 32; mm; mm >>= 1) s += __shfl_xor(s, mm, 64);
  if ((t & 63) == 0) red[t >> 6] = s;
  __syncthreads();
  if (t == 0) rdsh = 1.0f / (red[0] + red[1] + red[2] + red[3]);
  __syncthreads();
  const float rd = rdsh;

  const float* pb = partials + (size_t)b * NCHUNK * 256;
  float num = 0.f;
#pragma unroll 4
  for (int i = 0; i < NCHUNK; ++i) num += pb[i * 256 + t];
  out[b * HE_ + t] = num * rd;

  float* wout = out + B_ * HE_ + (size_t)b * S_;
#pragma unroll 4
  for (int i = t; i < S_; i += 256) wout[i] = we[i] * rd;
}

extern "C" void kernel_launch(void* const* d_in, const int* in_sizes, int n_in,
                              void* d_out, int out_size, void* d_ws, size_t ws_size,
                              hipStream_t stream) {
  const float* query = (const float*)d_in[0];
  const float* keys  = (const float*)d_in[1];
  const float* Wa_w  = (const float*)d_in[2];
  const float* Wa_b  = (const float*)d_in[3];
  const float* Ua_w  = (const float*)d_in[4];
  const float* Ua_b  = (const float*)d_in[5];
  const float* Va_w  = (const float*)d_in[6];
  // Va_b (d_in[7]) is a constant score shift: softmax-invariant, dropped.
  float* out = (float*)d_out;

  char* ws = (char*)d_ws;
  float* qv             = (float*)ws;                               // 32 KB
  unsigned short* ua_bf = (unsigned short*)(ws + 32 * 1024);        // 128 KB
  float* wexp_g         = (float*)(ws + 160 * 1024);                // 1 MB
  float* partials       = (float*)(ws + 160 * 1024 + 1048576);      // 1 MB

  prep_kernel<<<64, 256, 0, stream>>>(query, Wa_w, Wa_b, Ua_w, Ua_b, qv, ua_bf);
  dim3 g(NCHUNK, B_);
  main_kernel<<<g, 512, 0, stream>>>(keys, qv, Va_w, ua_bf, wexp_g, partials);
  combine_kernel<<<B_, 256, 0, stream>>>(wexp_g, partials, out);
}

// Round 18
// 75.876 us; speedup vs baseline: 1.0278x; 1.0278x over previous
//
#include <hip/hip_runtime.h>
#include <hip/hip_bf16.h>
#include <stdint.h>

#define B_ 32
#define S_ 8192
#define HD_ 256
#define HE_ 256
#define CHUNK 512
#define ROWS 16              /* rows per step */
#define MSTEPS (CHUNK/ROWS)  /* 32 steps */
#define NCHUNK (S_/CHUNK)    /* 16 chunks per batch */
#define TILE (ROWS * 512)    /* 8 KB per keys tile */

typedef __attribute__((ext_vector_type(8))) short bf16x8;
typedef __attribute__((ext_vector_type(4))) float f32x4;

__device__ __forceinline__ uint32_t cvt_pk_bf16(float lo, float hi) {
  uint32_t r;
  asm("v_cvt_pk_bf16_f32 %0, %1, %2" : "=v"(r) : "v"(lo), "v"(hi));
  return r;
}
__device__ __forceinline__ float bf2f(unsigned short h) {
  return __uint_as_float(((uint32_t)h) << 16);
}
__device__ __forceinline__ float tanh_fast(float x) {
  // tanh(x) = 1 - 2/(exp(2x)+1); well-behaved at +/-inf, no NaN
  float e = __expf(2.0f * x);
  return 1.0f - 2.0f * __builtin_amdgcn_rcpf(e + 1.0f);
}
// VALU cross-lane add within 16-lane DPP rows. Sum lands in lane 15 of each row.
template<int CTRL>
__device__ __forceinline__ float dpp_shr_add(float v) {
  int t = __builtin_amdgcn_update_dpp(0, __float_as_int(v), CTRL, 0xf, 0xf, true);
  return v + __int_as_float(t);
}
__device__ __forceinline__ float row16_sum(float v) {
  v = dpp_shr_add<0x118>(v);   // row_shr:8
  v = dpp_shr_add<0x114>(v);   // row_shr:4
  v = dpp_shr_add<0x112>(v);   // row_shr:2
  v = dpp_shr_add<0x111>(v);   // row_shr:1
  return v;                     // full sum valid in lane 15 of each 16-lane row
}

// ---------------- prep: qv[b,h] = q@Wa^T + Wa_b + Ua_b ; Ua -> bf16 ----------------
__global__ void prep_kernel(const float* __restrict__ query,
                            const float* __restrict__ Wa_w,
                            const float* __restrict__ Wa_b,
                            const float* __restrict__ Ua_w,
                            const float* __restrict__ Ua_b,
                            float* __restrict__ qv,
                            unsigned short* __restrict__ ua_bf) {
  const int blk = blockIdx.x, t = threadIdx.x;
  if (blk < B_) {
    __shared__ float qs[HD_];
    qs[t] = query[blk * HD_ + t];
    __syncthreads();
    const float* wr = Wa_w + (size_t)t * HD_;
    float s = Wa_b[t] + Ua_b[t];
#pragma unroll 8
    for (int d = 0; d < HD_; ++d) s += qs[d] * wr[d];
    qv[blk * HD_ + t] = s;
  } else {
    const int base = (blk - B_) * 2048 + t * 8;
    float4 v0 = *(const float4*)(Ua_w + base);
    float4 v1 = *(const float4*)(Ua_w + base + 4);
    uint4 pk;
    pk.x = cvt_pk_bf16(v0.x, v0.y);
    pk.y = cvt_pk_bf16(v0.z, v0.w);
    pk.z = cvt_pk_bf16(v1.x, v1.y);
    pk.w = cvt_pk_bf16(v1.z, v1.w);
    *(uint4*)(ua_bf + base) = pk;
  }
}

// ---------------- main: fused k_proj GEMM + tanh + score-exp + context partial ----------------
// v19 = R15 (verified best, 76.36 us): single-barrier pipelined schedule, 8-wave
// register-feasible geometry, CHUNK=512 (prologue amortized over 32 steps; grid 512 =
// 2 blocks/CU), wexp buffered in LDS and flushed in the epilogue (loop's only vmem ops
// are the 2 staged float4 loads -> shortest possible vmcnt drain at each barrier).
// Per step: issue L(i+1) | MFMA buf[i&3] | exp+wexp+numerator tile i-1 | tanh/DPP/atomic
// -> sc3[i%3] | zero sc3[(i+1)%3] | stage buf[(i+1)&3] | barrier.
__global__ __launch_bounds__(512)
__attribute__((amdgpu_waves_per_eu(4, 4)))
void main_kernel(const float* __restrict__ keys,
                 const float* __restrict__ qv,
                 const float* __restrict__ Va_w,
                 const unsigned short* __restrict__ ua_bf,
                 float* __restrict__ wexp_g,
                 float* __restrict__ partials) {
  __shared__ __align__(16) char kt[4 * TILE];          // 4 x (16 rows x 512B bf16), swizzled
  __shared__ float sc3[3][16];                          // triple-buffered row scores
  __shared__ float wexp_l[CHUNK];                       // per-chunk exp(score), flushed at end
  __shared__ __align__(16) float num_l[8][64][4];       // per-wave numerator partials (8 KB)

  const int t = threadIdx.x;
  const int b = blockIdx.y;
  const int chunk = blockIdx.x;
  const int s0 = chunk * CHUNK;
  const int lane = t & 63;
  const int w = t >> 6;               // wave 0..7
  const int ln = lane & 15;
  const int hi = lane >> 4;

  // ---- B fragments: wave w's 32 h-cols, 2 h-tiles, read ONCE (64 regs) ----
  const unsigned short* ub0 = ua_bf + (size_t)(w * 32 + ln) * HE_ + hi * 8;
  const unsigned short* ub1 = ub0 + 16 * HE_;
  bf16x8 bb0[8], bb1[8];
#pragma unroll
  for (int k = 0; k < 8; ++k) {
    bb0[k] = *(const bf16x8*)(ub0 + k * 32);
    bb1[k] = *(const bf16x8*)(ub1 + k * 32);
  }
  const float q0  = qv[b * HD_ + w * 32 + ln];
  const float q1  = qv[b * HD_ + w * 32 + 16 + ln];
  const float va0 = Va_w[w * 32 + ln];
  const float va1 = Va_w[w * 32 + 16 + ln];

  // ---- staging geometry: thread t handles row t>>5, 16B bf16 chunk t&31 ----
  const int srow = t >> 5;            // 0..15
  const int scch = t & 31;            // 16B bf16 chunk within 512B row
  const float* ksrc = keys + ((size_t)b * S_ + s0 + srow) * HE_ + scch * 8;
  const int ldsoff = srow * 512 + ((scch * 16) ^ ((srow & 7) << 4));

  // ---- prologue: zero sc3; stage tile 0 into buf0 ----
  if (t < 48) ((float*)sc3)[t] = 0.f;
  {
    float4 a0 = *(const float4*)(ksrc);
    float4 a1 = *(const float4*)(ksrc + 4);
    uint4 pk;
    pk.x = cvt_pk_bf16(a0.x, a0.y);
    pk.y = cvt_pk_bf16(a0.z, a0.w);
    pk.z = cvt_pk_bf16(a1.x, a1.y);
    pk.w = cvt_pk_bf16(a1.z, a1.w);
    *(uint4*)(kt + ldsoff) = pk;
  }
  __syncthreads();

  const int asw = (ln & 7) << 4;      // A-frag row swizzle
  const int nsw = (w & 7) << 4;       // numerator row swizzle ((w+8)&7 == w&7)
  float num4[4] = {0.f, 0.f, 0.f, 0.f};

  for (int i = 0; i < MSTEPS; ++i) {
    char* cur = kt + (i & 3) * TILE;
    char* stg = kt + ((i + 1) & 3) * TILE;
    char* prv = kt + ((i + 3) & 3) * TILE;   // buf[i-1]

    // issue next-tile global loads early (in flight across MFMA/tanh/num)
    float4 ga0, ga1;
    if (i + 1 < MSTEPS) {
      const float* kA = ksrc + (size_t)(i + 1) * ROWS * HE_;
      ga0 = *(const float4*)(kA);
      ga1 = *(const float4*)(kA + 4);
    }

    // ---- MFMA tile i: 1 M-subtile x 2 h-tiles; A-frags just-in-time from LDS ----
    f32x4 a00 = {0.f,0.f,0.f,0.f}, a01 = {0.f,0.f,0.f,0.f};
    const char* arow = cur + ln * 512;
#pragma unroll
    for (int k = 0; k < 8; ++k) {
      bf16x8 af = *(const bf16x8*)(arow + ((k * 64 + hi * 16) ^ asw));
      a00 = __builtin_amdgcn_mfma_f32_16x16x32_bf16(af, bb0[k], a00, 0, 0, 0);
      a01 = __builtin_amdgcn_mfma_f32_16x16x32_bf16(af, bb1[k], a01, 0, 0, 0);
    }

    // ---- lagged: exp + wexp(LDS) + numerator for tile i-1 ----
    if (i > 0) {
      const float* scp = sc3[(i + 2) % 3];   // sc[i-1], complete since last barrier
      const float e0 = __expf(scp[w]);
      const float e8 = __expf(scp[w + 8]);
      if (lane == 0) {
        wexp_l[(i - 1) * ROWS + w] = e0;
        wexp_l[(i - 1) * ROWS + 8 + w] = e8;
      }
      uint2 kv0 = *(const uint2*)(prv + w * 512 + ((lane * 8) ^ nsw));
      uint2 kv1 = *(const uint2*)(prv + (w + 8) * 512 + ((lane * 8) ^ nsw));
      num4[0] += e0 * bf2f((unsigned short)(kv0.x & 0xffff)) + e8 * bf2f((unsigned short)(kv1.x & 0xffff));
      num4[1] += e0 * bf2f((unsigned short)(kv0.x >> 16))    + e8 * bf2f((unsigned short)(kv1.x >> 16));
      num4[2] += e0 * bf2f((unsigned short)(kv0.y & 0xffff)) + e8 * bf2f((unsigned short)(kv1.y & 0xffff));
      num4[3] += e0 * bf2f((unsigned short)(kv0.y >> 16))    + e8 * bf2f((unsigned short)(kv1.y >> 16));
    }

    // ---- tanh + DPP reduce + atomic into sc[i] ----
#pragma unroll
    for (int r = 0; r < 4; ++r) {
      float v = tanh_fast(a00[r] + q0) * va0 + tanh_fast(a01[r] + q1) * va1;
      v = row16_sum(v);
      if (ln == 15) atomicAdd(&sc3[i % 3][hi * 4 + r], v);
    }

    if (t < 16) sc3[(i + 1) % 3][t] = 0.f;   // zero next-step accumulator (unread this step)

    // ---- stage tile i+1 (vmcnt wait lands here, after all independent work) ----
    if (i + 1 < MSTEPS) {
      uint4 pk;
      pk.x = cvt_pk_bf16(ga0.x, ga0.y);
      pk.y = cvt_pk_bf16(ga0.z, ga0.w);
      pk.z = cvt_pk_bf16(ga1.x, ga1.y);
      pk.w = cvt_pk_bf16(ga1.z, ga1.w);
      *(uint4*)(stg + ldsoff) = pk;
    }
    __syncthreads();   // single barrier: publishes sc[i] + buf[i+1]; retires buf[i-1]
  }

  // ---- epilogue: tile MSTEPS-1 exp + wexp + numerator ----
  {
    const float* scp = sc3[(MSTEPS - 1) % 3];
    const char* prv = kt + ((MSTEPS - 1) & 3) * TILE;
    const float e0 = __expf(scp[w]);
    const float e8 = __expf(scp[w + 8]);
    if (lane == 0) {
      wexp_l[(MSTEPS - 1) * ROWS + w] = e0;
      wexp_l[(MSTEPS - 1) * ROWS + 8 + w] = e8;
    }
    uint2 kv0 = *(const uint2*)(prv + w * 512 + ((lane * 8) ^ nsw));
    uint2 kv1 = *(const uint2*)(prv + (w + 8) * 512 + ((lane * 8) ^ nsw));
    num4[0] += e0 * bf2f((unsigned short)(kv0.x & 0xffff)) + e8 * bf2f((unsigned short)(kv1.x & 0xffff));
    num4[1] += e0 * bf2f((unsigned short)(kv0.x >> 16))    + e8 * bf2f((unsigned short)(kv1.x >> 16));
    num4[2] += e0 * bf2f((unsigned short)(kv0.y & 0xffff)) + e8 * bf2f((unsigned short)(kv1.y & 0xffff));
    num4[3] += e0 * bf2f((unsigned short)(kv0.y >> 16))    + e8 * bf2f((unsigned short)(kv1.y >> 16));
  }

  // ---- flush wexp + cross-wave numerator reduce ----
  *(float4*)&num_l[w][lane][0] = make_float4(num4[0], num4[1], num4[2], num4[3]);
  __syncthreads();
  wexp_g[(size_t)b * S_ + s0 + t] = wexp_l[t];   // CHUNK == blockDim: one coalesced store
  if (t < 256) {
    float s = 0.f;
#pragma unroll
    for (int ww = 0; ww < 8; ++ww) s += num_l[ww][t >> 2][t & 3];
    partials[((size_t)b * NCHUNK + chunk) * 256 + t] = s;
  }
}

// ---------------- combine: den + context + weights per batch ----------------
__global__ void combine_kernel(const float* __restrict__ wexp_g,
                               const float* __restrict__ partials,
                               float* __restrict__ out) {
  __shared__ float red[4];
  __shared__ float rdsh;
  const int b = blockIdx.x, t = threadIdx.x;   // 256 threads
  const float* we = wexp_g + (size_t)b * S_;
  float s = 0.f;
#pragma unroll 4
  for (int i = t; i < S_; i += 256) s += we[i];
#pragma unroll
  for (int mm = 32; mm; mm >>= 1) s += __shfl_xor(s, mm, 64);
  if ((t & 63) == 0) red[t >> 6] = s;
  __syncthreads();
  if (t == 0) rdsh = 1.0f / (red[0] + red[1] + red[2] + red[3]);
  __syncthreads();
  const float rd = rdsh;

  const float* pb = partials + (size_t)b * NCHUNK * 256;
  float num = 0.f;
#pragma unroll 4
  for (int i = 0; i < NCHUNK; ++i) num += pb[i * 256 + t];
  out[b * HE_ + t] = num * rd;

  float* wout = out + B_ * HE_ + (size_t)b * S_;
#pragma unroll 4
  for (int i = t; i < S_; i += 256) wout[i] = we[i] * rd;
}

extern "C" void kernel_launch(void* const* d_in, const int* in_sizes, int n_in,
                              void* d_out, int out_size, void* d_ws, size_t ws_size,
                              hipStream_t stream) {
  const float* query = (const float*)d_in[0];
  const float* keys  = (const float*)d_in[1];
  const float* Wa_w  = (const float*)d_in[2];
  const float* Wa_b  = (const float*)d_in[3];
  const float* Ua_w  = (const float*)d_in[4];
  const float* Ua_b  = (const float*)d_in[5];
  const float* Va_w  = (const float*)d_in[6];
  // Va_b (d_in[7]) is a constant score shift: softmax-invariant, dropped.
  float* out = (float*)d_out;

  char* ws = (char*)d_ws;
  float* qv             = (float*)ws;                               // 32 KB
  unsigned short* ua_bf = (unsigned short*)(ws + 32 * 1024);        // 128 KB
  float* wexp_g         = (float*)(ws + 160 * 1024);                // 1 MB
  float* partials       = (float*)(ws + 160 * 1024 + 1048576);      // 1 MB

  prep_kernel<<<64, 256, 0, stream>>>(query, Wa_w, Wa_b, Ua_w, Ua_b, qv, ua_bf);
  dim3 g(NCHUNK, B_);
  main_kernel<<<g, 512, 0, stream>>>(keys, qv, Va_w, ua_bf, wexp_g, partials);
  combine_kernel<<<B_, 256, 0, stream>>>(wexp_g, partials, out);
}